// Round 4
// baseline (284.834 us; speedup 1.0000x reference)
//
#include <hip/hip_runtime.h>
#include <hip/hip_bf16.h>

#define XDIM 14087   // 4*3481 conv + 162 atm + 1 egfn1
#define NATM 81
#define BS   128
#define KC   128          // K-chunk for fc1 GEMM
#define NKCH 111          // ceil(14087/128)

__device__ __forceinline__ float fast_rcp(float x) {
    return __builtin_amdgcn_rcpf(x);
}
__device__ __forceinline__ float silu(float z) {
    return z * fast_rcp(1.f + __expf(-z));
}
__device__ __forceinline__ float leaky(float z) {
    return (z > 0.f) ? z : 0.01f * z;
}

// ---------------------------------------------------------------------------
// EGNN: one block per (r,b). 486 active threads = 81 i-nodes x 3 j-parts x 2 k2-halves.
// Writes atm (cols 13924..14085) and egfn1 (col 14086) of xbuf row.
// Issue-bound at ~8 waves/CU; ~10 us total. Left as-is.
// ---------------------------------------------------------------------------
__global__ __launch_bounds__(512) void egnn_kernel(
    const float* __restrict__ xyz, const float* __restrict__ cn,
    const float* __restrict__ edisp, const float* __restrict__ egfn1,
    const float* __restrict__ We1, const float* __restrict__ be1,
    const float* __restrict__ We2, const float* __restrict__ be2,
    const float* __restrict__ Wn1, const float* __restrict__ bn1,
    const float* __restrict__ Wn2, const float* __restrict__ bn2,
    float* __restrict__ xbuf)
{
    const int bid = blockIdx.x;      // r*128 + b
    const int tid = threadIdx.x;

    __shared__ float sc[NATM][3];
    __shared__ float sf[NATM][2];
    __shared__ float sai[NATM][10];
    __shared__ float sbj[NATM][10];
    __shared__ float sW2[160];
    __shared__ float sbe2[16];
    __shared__ float sw5[10];
    __shared__ float sWn1[72];
    __shared__ float sbn1[4];
    __shared__ float sWn2[8];
    __shared__ float sbn2[2];
    __shared__ float smp[3][NATM][17];   // padded stride 17 to break bank conflicts

    const float* xb = xyz + (size_t)bid * NATM * 3;
    for (int idx = tid; idx < NATM * 3; idx += 512) sc[idx / 3][idx % 3] = xb[idx];
    if (tid < NATM) {
        const float f0 = cn[(size_t)bid * NATM + tid];
        const float f1 = edisp[(size_t)bid * NATM + tid];
        sf[tid][0] = f0; sf[tid][1] = f1;
        #pragma unroll
        for (int k = 0; k < 10; ++k) {
            sai[tid][k] = be1[k] + We1[k * 5 + 0] * f0 + We1[k * 5 + 1] * f1;
            sbj[tid][k] =          We1[k * 5 + 2] * f0 + We1[k * 5 + 3] * f1;
        }
    }
    if (tid < 160) sW2[tid] = We2[tid];
    if (tid < 16)  sbe2[tid] = be2[tid];
    if (tid < 10)  sw5[tid] = We1[tid * 5 + 4];
    if (tid < 72)  sWn1[tid] = Wn1[tid];
    if (tid < 4)   sbn1[tid] = bn1[tid];
    if (tid < 8)   sWn2[tid] = Wn2[tid];
    if (tid < 2)   sbn2[tid] = bn2[tid];
    __syncthreads();

    if (tid < 486) {
        const int i    = tid % 81;
        const int part = (tid / 81) % 3;
        const int half = tid / 243;      // 0 or 1: which 8 of the 16 m-channels

        float W2r[80];
        #pragma unroll
        for (int q = 0; q < 80; ++q) W2r[q] = sW2[half * 80 + q];
        float be2r[8];
        #pragma unroll
        for (int q = 0; q < 8; ++q) be2r[q] = sbe2[half * 8 + q];
        float w5r[10];
        #pragma unroll
        for (int k = 0; k < 10; ++k) w5r[k] = sw5[k];
        float air[10];
        #pragma unroll
        for (int k = 0; k < 10; ++k) air[k] = sai[i][k];
        const float ci0 = sc[i][0], ci1 = sc[i][1], ci2 = sc[i][2];

        float macc[8];
        #pragma unroll
        for (int q = 0; q < 8; ++q) macc[q] = 0.f;

        const int j0 = part * 27;
        for (int j = j0; j < j0 + 27; ++j) {
            const float dx = ci0 - sc[j][0];
            const float dy = ci1 - sc[j][1];
            const float dz = ci2 - sc[j][2];
            const float rd = dx * dx + dy * dy + dz * dz;
            float h[10];
            #pragma unroll
            for (int k = 0; k < 10; ++k) {
                const float z = air[k] + sbj[j][k] + w5r[k] * rd;
                h[k] = silu(z);
            }
            #pragma unroll
            for (int q = 0; q < 8; ++q) {
                float z = be2r[q];
                #pragma unroll
                for (int k = 0; k < 10; ++k) z += W2r[q * 10 + k] * h[k];
                macc[q] += silu(z);
            }
        }
        #pragma unroll
        for (int q = 0; q < 8; ++q) smp[part][i][half * 8 + q] = macc[q];
    }
    __syncthreads();

    if (tid < NATM) {
        float mi[16];
        #pragma unroll
        for (int q = 0; q < 16; ++q)
            mi[q] = smp[0][tid][q] + smp[1][tid][q] + smp[2][tid][q];
        const float f0 = sf[tid][0], f1 = sf[tid][1];
        float n1[4];
        #pragma unroll
        for (int k = 0; k < 4; ++k) {
            float z = sbn1[k] + sWn1[k * 18 + 0] * f0 + sWn1[k * 18 + 1] * f1;
            #pragma unroll
            for (int q = 0; q < 16; ++q) z += sWn1[k * 18 + 2 + q] * mi[q];
            n1[k] = silu(z);
        }
        float* xrow = xbuf + (size_t)bid * XDIM + 13924 + tid * 2;
        #pragma unroll
        for (int c = 0; c < 2; ++c) {
            float z = sbn2[c] + (c ? f1 : f0);
            #pragma unroll
            for (int k = 0; k < 4; ++k) z += sWn2[c * 4 + k] * n1[k];
            xrow[c] = z;
        }
    }
    if (tid == 0) xbuf[(size_t)bid * XDIM + 14086] = egfn1[bid];
}

// ---------------------------------------------------------------------------
// Fused conv block, v3: each thread computes a 1x2 pair of final pixels
// (y, 2q) and (y, 2q+1). Shares the overlapping pool1 column between the two
// finals (conv1 evals 60 vs 72 per pair) and folds leaky through both max-
// pools (exact: leaky is monotone, maxpool(leaky(x)) == leaky(maxpool(x))).
// Block 256 thr = 8 output rows x 32 pair-slots (30 active). Grid 512*8.
// ---------------------------------------------------------------------------
__global__ __launch_bounds__(256) void conv_kernel(
    const float* __restrict__ ovlp, const float* __restrict__ h0,
    const float* __restrict__ w1, const float* __restrict__ b1,
    const float* __restrict__ w2, const float* __restrict__ b2,
    float* __restrict__ xbuf)
{
    const int bid   = blockIdx.x;
    const int strip = bid & 7;           // 8 strips x 8 rows = 64 >= 59
    const int img   = bid >> 3;          // r*256 + t*128 + b
    const int b     = img & 127;
    const int t     = (img >> 7) & 1;
    const int r     = img >> 8;
    const int tid   = threadIdx.x;

    const int q    = tid & 31;           // pair index (0..29 active)
    const int slot = tid >> 5;           // output row within strip
    const int y    = strip * 8 + slot;
    const int qc   = (q < 30) ? q : 29;  // clamp for idle lanes
    const int yc   = (y < 59) ? y : 58;

    const float4* src4 = reinterpret_cast<const float4*>(
        (t ? h0 : ovlp) + (size_t)(r * BS + b) * 57600);

    float w1r[8], w2r[16], b1r[2], b2r[2];
    #pragma unroll
    for (int k = 0; k < 8; ++k) w1r[k] = w1[k];
    #pragma unroll
    for (int k = 0; k < 16; ++k) w2r[k] = w2[k];
    b1r[0] = b1[0]; b1r[1] = b1[1];
    b2r[0] = b2[0]; b2r[1] = b2[1];

    // 7x12 input patch: rows 4yc..4yc+6, cols 8qc..8qc+11.
    // q=29 would read f4 index 60 (col 240, OOB) -> clamp to 59; the garbage
    // cols feed only the masked final x=59.
    float P[7][12];
    const int rbase = 4 * yc * 60 + 2 * qc;
    #pragma unroll
    for (int rr = 0; rr < 7; ++rr) {
        #pragma unroll
        for (int c4 = 0; c4 < 3; ++c4) {
            const int ci = 2 * qc + c4;
            const float4 v = src4[4 * yc * 60 + rr * 60 + ((ci < 60) ? ci : 59)];
            P[rr][c4 * 4 + 0] = v.x; P[rr][c4 * 4 + 1] = v.y;
            P[rr][c4 * 4 + 2] = v.z; P[rr][c4 * 4 + 3] = v.w;
        }
    }

    // conv1 -> max-pool -> leaky (folded): p1[2][3][5]
    float p1[2][3][5];
    #pragma unroll
    for (int c = 0; c < 2; ++c) {
        const float wa = w1r[c * 4 + 0], wb = w1r[c * 4 + 1];
        const float wc = w1r[c * 4 + 2], wd = w1r[c * 4 + 3];
        const float bb = b1r[c];
        #pragma unroll
        for (int pr = 0; pr < 3; ++pr)
        #pragma unroll
        for (int pc = 0; pc < 5; ++pc) {
            float mx = -3.4e38f;
            #pragma unroll
            for (int s = 0; s < 2; ++s)
            #pragma unroll
            for (int tt = 0; tt < 2; ++tt) {
                const int u = 2 * pr + s, v = 2 * pc + tt;
                const float raw = fmaf(wa, P[u][v], fmaf(wb, P[u][v + 1],
                                  fmaf(wc, P[u + 1][v], fmaf(wd, P[u + 1][v + 1], bb))));
                mx = fmaxf(mx, raw);
            }
            p1[c][pr][pc] = leaky(mx);
        }
    }

    // conv2 -> max-pool -> leaky (folded) -> two finals
    const bool wy = (y < 59) && (q < 30);
    float* xrow = xbuf + (size_t)(r * BS + b) * XDIM + (size_t)(t * 2) * 3481
                  + y * 59 + 2 * q;
    #pragma unroll
    for (int c2 = 0; c2 < 2; ++c2) {
        #pragma unroll
        for (int fx = 0; fx < 2; ++fx) {
            float mx = -3.4e38f;
            #pragma unroll
            for (int a2 = 0; a2 < 2; ++a2)
            #pragma unroll
            for (int b2i = 0; b2i < 2; ++b2i) {
                const int cc = 2 * fx + b2i;
                float acc = b2r[c2];
                #pragma unroll
                for (int c1 = 0; c1 < 2; ++c1)
                #pragma unroll
                for (int du = 0; du < 2; ++du)
                #pragma unroll
                for (int dv = 0; dv < 2; ++dv)
                    acc += w2r[((c2 * 2 + c1) * 2 + du) * 2 + dv]
                         * p1[c1][a2 + du][cc + dv];
                mx = fmaxf(mx, acc);
            }
            if (wy && (2 * q + fx < 59))
                xrow[(size_t)c2 * 3481 + fx] = leaky(mx);
        }
    }
}

// ---------------------------------------------------------------------------
// fc1 as tiled split-K GEMM:  psum[kc][row][n] = sum_{k in chunk kc} X[row][k]*W1[n][k]
// Grid: (NKCH, 8 m-tiles). Block 256 thr: tile M=32, N=64(60 used), K=128.
// ---------------------------------------------------------------------------
__global__ __launch_bounds__(256) void gemm_fc1_kernel(
    const float* __restrict__ xbuf, const float* __restrict__ fc1w,
    float* __restrict__ psum)
{
    const int kc   = blockIdx.x;
    const int mt   = blockIdx.y;
    const int tid  = threadIdx.x;
    const int kbase = kc * KC;
    const int rem   = min(KC, XDIM - kbase);   // 7 on last chunk
    const int row0  = mt * 32;

    __shared__ float4 X4[32][33];   // [m][k4], row stride 132 floats (2-way banks: free)
    __shared__ float4 W4[64][33];   // [n][k4]

    float* Xs = reinterpret_cast<float*>(&X4[0][0]);
    float* Ws = reinterpret_cast<float*>(&W4[0][0]);

    for (int idx = tid; idx < 32 * KC; idx += 256) {
        const int m = idx >> 7, k = idx & 127;
        Xs[m * 132 + k] = (k < rem) ? xbuf[(size_t)(row0 + m) * XDIM + kbase + k] : 0.f;
    }
    for (int idx = tid; idx < 64 * KC; idx += 256) {
        const int n = idx >> 7, k = idx & 127;
        Ws[n * 132 + k] = (n < 60 && k < rem) ? fc1w[(size_t)n * XDIM + kbase + k] : 0.f;
    }
    __syncthreads();

    const int ty = tid >> 4, tx = tid & 15;
    const int m0 = ty * 2;

    float acc[2][4];
    #pragma unroll
    for (int i = 0; i < 2; ++i)
    #pragma unroll
    for (int j = 0; j < 4; ++j) acc[i][j] = 0.f;

    #pragma unroll 4
    for (int k4 = 0; k4 < 32; ++k4) {
        const float4 xa = X4[m0][k4];
        const float4 xb = X4[m0 + 1][k4];
        #pragma unroll
        for (int j = 0; j < 4; ++j) {
            const float4 w = W4[tx + 16 * j][k4];
            acc[0][j] += xa.x * w.x + xa.y * w.y + xa.z * w.z + xa.w * w.w;
            acc[1][j] += xb.x * w.x + xb.y * w.y + xb.z * w.z + xb.w * w.w;
        }
    }

    float* po = psum + ((size_t)kc * 256 + row0) * 64;
    #pragma unroll
    for (int i = 0; i < 2; ++i)
    #pragma unroll
    for (int j = 0; j < 4; ++j)
        po[(size_t)(m0 + i) * 64 + tx + 16 * j] = acc[i][j];
}

// ---------------------------------------------------------------------------
// Tail: reduce psum over chunks, bias+leaky, fc2, fc3, * nu, sum over r.
// Grid 128 (one block per b), 128 threads (wave 0 -> r=0, wave 1 -> r=1).
// Deterministic (no atomics).
// ---------------------------------------------------------------------------
__global__ __launch_bounds__(128) void fc_tail_kernel(
    const float* __restrict__ psum,
    const float* __restrict__ fc1b,
    const float* __restrict__ fc2w, const float* __restrict__ fc2b,
    const float* __restrict__ fc3w, const float* __restrict__ fc3b,
    const float* __restrict__ nu, float* __restrict__ out)
{
    const int b = blockIdx.x;
    const int tid = threadIdx.x;
    const int rh = tid >> 6;        // which r
    const int n  = tid & 63;

    __shared__ float y1s[2][64];
    __shared__ float y2s[2][30];

    const int row = rh * 128 + b;
    float s = 0.f;
    #pragma unroll 8
    for (int kcc = 0; kcc < NKCH; ++kcc)
        s += psum[((size_t)kcc * 256 + row) * 64 + n];
    y1s[rh][n] = (n < 60) ? leaky(s + fc1b[n]) : 0.f;
    __syncthreads();

    if (n < 30) {
        float a2 = fc2b[n];
        const float* wr = fc2w + n * 60;
        #pragma unroll
        for (int k = 0; k < 60; ++k) a2 += wr[k] * y1s[rh][k];
        y2s[rh][n] = leaky(a2);
    }
    __syncthreads();

    if (tid == 0) {
        float acc_out = 0.f;
        #pragma unroll
        for (int r = 0; r < 2; ++r) {
            float a3 = fc3b[0];
            #pragma unroll
            for (int k = 0; k < 30; ++k) a3 += fc3w[k] * y2s[r][k];
            acc_out += a3 * nu[b * 2 + r];
        }
        out[b] = acc_out;
    }
}

extern "C" void kernel_launch(void* const* d_in, const int* in_sizes, int n_in,
                              void* d_out, int out_size, void* d_ws, size_t ws_size,
                              hipStream_t stream)
{
    const float* xyz   = (const float*)d_in[0];
    const float* cn    = (const float*)d_in[1];
    const float* edisp = (const float*)d_in[2];
    const float* ovlp  = (const float*)d_in[3];
    const float* h0    = (const float*)d_in[4];
    const float* egfn1 = (const float*)d_in[5];
    const float* nu    = (const float*)d_in[6];
    const float* We1   = (const float*)d_in[7];
    const float* be1   = (const float*)d_in[8];
    const float* We2   = (const float*)d_in[9];
    const float* be2   = (const float*)d_in[10];
    // d_in[11..15] = Wc1,bc1,Wc2,bc2,coors_scale: dead code (coors_out discarded)
    const float* Wn1   = (const float*)d_in[16];
    const float* bn1   = (const float*)d_in[17];
    const float* Wn2   = (const float*)d_in[18];
    const float* bn2   = (const float*)d_in[19];
    const float* c1w   = (const float*)d_in[20];
    const float* c1b   = (const float*)d_in[21];
    const float* c2w   = (const float*)d_in[22];
    const float* c2b   = (const float*)d_in[23];
    const float* fc1w  = (const float*)d_in[24];
    const float* fc1b  = (const float*)d_in[25];
    const float* fc2w  = (const float*)d_in[26];
    const float* fc2b  = (const float*)d_in[27];
    const float* fc3w  = (const float*)d_in[28];
    const float* fc3b  = (const float*)d_in[29];

    float* xbuf = (float*)d_ws;                         // 256 x 14087 f32 = 14.43 MB
    float* psum = (float*)((char*)d_ws + 14425088);     // 111 x 256 x 64 f32 = 7.27 MB
    float* out  = (float*)d_out;

    hipLaunchKernelGGL(egnn_kernel, dim3(256), dim3(512), 0, stream,
                       xyz, cn, edisp, egfn1, We1, be1, We2, be2,
                       Wn1, bn1, Wn2, bn2, xbuf);
    hipLaunchKernelGGL(conv_kernel, dim3(512 * 8), dim3(256), 0, stream,
                       ovlp, h0, c1w, c1b, c2w, c2b, xbuf);
    hipLaunchKernelGGL(gemm_fc1_kernel, dim3(NKCH, 8), dim3(256), 0, stream,
                       xbuf, fc1w, psum);
    hipLaunchKernelGGL(fc_tail_kernel, dim3(128), dim3(128), 0, stream,
                       psum, fc1b, fc2w, fc2b, fc3w, fc3b, nu, out);
}

// Round 5
// 272.403 us; speedup vs baseline: 1.0456x; 1.0456x over previous
//
#include <hip/hip_runtime.h>
#include <hip/hip_bf16.h>

#define XDIM 14087   // 4*3481 conv + 162 atm + 1 egfn1
#define NATM 81
#define BS   128
#define KC   128          // K-chunk for fc1 GEMM
#define NKCH 111          // ceil(14087/128)

__device__ __forceinline__ float fast_rcp(float x) {
    return __builtin_amdgcn_rcpf(x);
}
__device__ __forceinline__ float silu(float z) {
    return z * fast_rcp(1.f + __expf(-z));
}
__device__ __forceinline__ float leaky(float z) {
    return (z > 0.f) ? z : 0.01f * z;
}

// ---------------------------------------------------------------------------
// EGNN: one block per (r,b). 486 active threads = 81 i-nodes x 3 j-parts x 2 k2-halves.
// Writes atm (cols 13924..14085) and egfn1 (col 14086) of xbuf row.
// ---------------------------------------------------------------------------
__global__ __launch_bounds__(512) void egnn_kernel(
    const float* __restrict__ xyz, const float* __restrict__ cn,
    const float* __restrict__ edisp, const float* __restrict__ egfn1,
    const float* __restrict__ We1, const float* __restrict__ be1,
    const float* __restrict__ We2, const float* __restrict__ be2,
    const float* __restrict__ Wn1, const float* __restrict__ bn1,
    const float* __restrict__ Wn2, const float* __restrict__ bn2,
    float* __restrict__ xbuf)
{
    const int bid = blockIdx.x;      // r*128 + b
    const int tid = threadIdx.x;

    __shared__ float sc[NATM][3];
    __shared__ float sf[NATM][2];
    __shared__ float sai[NATM][10];
    __shared__ float sbj[NATM][10];
    __shared__ float sW2[160];
    __shared__ float sbe2[16];
    __shared__ float sw5[10];
    __shared__ float sWn1[72];
    __shared__ float sbn1[4];
    __shared__ float sWn2[8];
    __shared__ float sbn2[2];
    __shared__ float smp[3][NATM][17];   // padded stride 17 to break bank conflicts

    const float* xb = xyz + (size_t)bid * NATM * 3;
    for (int idx = tid; idx < NATM * 3; idx += 512) sc[idx / 3][idx % 3] = xb[idx];
    if (tid < NATM) {
        const float f0 = cn[(size_t)bid * NATM + tid];
        const float f1 = edisp[(size_t)bid * NATM + tid];
        sf[tid][0] = f0; sf[tid][1] = f1;
        #pragma unroll
        for (int k = 0; k < 10; ++k) {
            sai[tid][k] = be1[k] + We1[k * 5 + 0] * f0 + We1[k * 5 + 1] * f1;
            sbj[tid][k] =          We1[k * 5 + 2] * f0 + We1[k * 5 + 3] * f1;
        }
    }
    if (tid < 160) sW2[tid] = We2[tid];
    if (tid < 16)  sbe2[tid] = be2[tid];
    if (tid < 10)  sw5[tid] = We1[tid * 5 + 4];
    if (tid < 72)  sWn1[tid] = Wn1[tid];
    if (tid < 4)   sbn1[tid] = bn1[tid];
    if (tid < 8)   sWn2[tid] = Wn2[tid];
    if (tid < 2)   sbn2[tid] = bn2[tid];
    __syncthreads();

    if (tid < 486) {
        const int i    = tid % 81;
        const int part = (tid / 81) % 3;
        const int half = tid / 243;      // 0 or 1: which 8 of the 16 m-channels

        float W2r[80];
        #pragma unroll
        for (int q = 0; q < 80; ++q) W2r[q] = sW2[half * 80 + q];
        float be2r[8];
        #pragma unroll
        for (int q = 0; q < 8; ++q) be2r[q] = sbe2[half * 8 + q];
        float w5r[10];
        #pragma unroll
        for (int k = 0; k < 10; ++k) w5r[k] = sw5[k];
        float air[10];
        #pragma unroll
        for (int k = 0; k < 10; ++k) air[k] = sai[i][k];
        const float ci0 = sc[i][0], ci1 = sc[i][1], ci2 = sc[i][2];

        float macc[8];
        #pragma unroll
        for (int q = 0; q < 8; ++q) macc[q] = 0.f;

        const int j0 = part * 27;
        for (int j = j0; j < j0 + 27; ++j) {
            const float dx = ci0 - sc[j][0];
            const float dy = ci1 - sc[j][1];
            const float dz = ci2 - sc[j][2];
            const float rd = dx * dx + dy * dy + dz * dz;
            float h[10];
            #pragma unroll
            for (int k = 0; k < 10; ++k) {
                const float z = air[k] + sbj[j][k] + w5r[k] * rd;
                h[k] = silu(z);
            }
            #pragma unroll
            for (int q = 0; q < 8; ++q) {
                float z = be2r[q];
                #pragma unroll
                for (int k = 0; k < 10; ++k) z += W2r[q * 10 + k] * h[k];
                macc[q] += silu(z);
            }
        }
        #pragma unroll
        for (int q = 0; q < 8; ++q) smp[part][i][half * 8 + q] = macc[q];
    }
    __syncthreads();

    if (tid < NATM) {
        float mi[16];
        #pragma unroll
        for (int q = 0; q < 16; ++q)
            mi[q] = smp[0][tid][q] + smp[1][tid][q] + smp[2][tid][q];
        const float f0 = sf[tid][0], f1 = sf[tid][1];
        float n1[4];
        #pragma unroll
        for (int k = 0; k < 4; ++k) {
            float z = sbn1[k] + sWn1[k * 18 + 0] * f0 + sWn1[k * 18 + 1] * f1;
            #pragma unroll
            for (int q = 0; q < 16; ++q) z += sWn1[k * 18 + 2 + q] * mi[q];
            n1[k] = silu(z);
        }
        float* xrow = xbuf + (size_t)bid * XDIM + 13924 + tid * 2;
        #pragma unroll
        for (int c = 0; c < 2; ++c) {
            float z = sbn2[c] + (c ? f1 : f0);
            #pragma unroll
            for (int k = 0; k < 4; ++k) z += sWn2[c * 4 + k] * n1[k];
            xrow[c] = z;
        }
    }
    if (tid == 0) xbuf[(size_t)bid * XDIM + 14086] = egfn1[bid];
}

// ---------------------------------------------------------------------------
// Fused conv block, v4: R3 memory pattern (wave = one output row, lane = one
// output col, direct coalesced loads, FETCH ~67MB) + two exact VALU cuts:
//  - leaky folded through both max-pools (monotone => exact; validated R4)
//  - cross-lane pool1 sharing: lane x computes pool1 cols {2x,2x+1} only
//    (48 conv1 evals vs 72) and gets col 2x+2 from lane x+1 via __shfl_down.
// All 64 lanes run (shuffle participation); stores masked to x<59.
// ---------------------------------------------------------------------------
__global__ __launch_bounds__(256) void conv_kernel(
    const float* __restrict__ ovlp, const float* __restrict__ h0,
    const float* __restrict__ w1, const float* __restrict__ b1,
    const float* __restrict__ w2, const float* __restrict__ b2,
    float* __restrict__ xbuf)
{
    const int bid   = blockIdx.x;
    const int strip = bid % 15;          // 15 strips x 4 rows = 60 >= 59
    const int img   = bid / 15;          // r*256 + t*128 + b
    const int b     = img & 127;
    const int t     = (img >> 7) & 1;
    const int r     = img >> 8;
    const int tid   = threadIdx.x;

    const int wv = tid >> 6;             // wave -> output row within strip
    const int l  = tid & 63;             // lane -> output col
    const int y  = strip * 4 + wv;
    if (y >= 59) return;                 // wave-uniform exit (y is uniform per wave)
    const int x  = l;
    const int xc = (x < 59) ? x : 59;    // lanes 59..63 clamp; lane 59 feeds lane 58

    const float* src = (t ? h0 : ovlp) + (size_t)(r * BS + b) * 57600;

    float w1r[8], w2r[16], b1r[2], b2r[2];
    #pragma unroll
    for (int k = 0; k < 8; ++k) w1r[k] = w1[k];
    #pragma unroll
    for (int k = 0; k < 16; ++k) w2r[k] = w2[k];
    b1r[0] = b1[0]; b1r[1] = b1[1];
    b2r[0] = b2[0]; b2r[1] = b2[1];

    // 7x5 input patch: rows 4y..4y+6, cols 4xc..4xc+4 (float4 + scalar).
    // xc=59: scalar reads col 240 -> wraps to next image row (in-bounds memory,
    // garbage data) -> flows only into pool col 119 -> only final x=59 (masked).
    float P[7][5];
    #pragma unroll
    for (int rr = 0; rr < 7; ++rr) {
        const float* rp = src + (4 * y + rr) * 240 + 4 * xc;
        const float4 a = *reinterpret_cast<const float4*>(rp);
        P[rr][0] = a.x; P[rr][1] = a.y; P[rr][2] = a.z; P[rr][3] = a.w;
        P[rr][4] = rp[4];
    }

    // conv1 -> pool (raw max) -> leaky: own pool1 cols {2x, 2x+1}
    float p1o[2][3][2];
    #pragma unroll
    for (int c = 0; c < 2; ++c) {
        const float wa = w1r[c * 4 + 0], wb = w1r[c * 4 + 1];
        const float wc = w1r[c * 4 + 2], wd = w1r[c * 4 + 3];
        const float bb = b1r[c];
        #pragma unroll
        for (int pr = 0; pr < 3; ++pr)
        #pragma unroll
        for (int pc = 0; pc < 2; ++pc) {
            float mx = -3.4e38f;
            #pragma unroll
            for (int s = 0; s < 2; ++s)
            #pragma unroll
            for (int tt = 0; tt < 2; ++tt) {
                const int u = 2 * pr + s, v = 2 * pc + tt;
                const float raw = fmaf(wa, P[u][v], fmaf(wb, P[u][v + 1],
                                  fmaf(wc, P[u + 1][v], fmaf(wd, P[u + 1][v + 1], bb))));
                mx = fmaxf(mx, raw);
            }
            p1o[c][pr][pc] = leaky(mx);
        }
    }

    // share pool1 col 2x+2 from lane x+1 (its pc=0)
    float p1[2][3][3];
    #pragma unroll
    for (int c = 0; c < 2; ++c)
    #pragma unroll
    for (int pr = 0; pr < 3; ++pr) {
        p1[c][pr][0] = p1o[c][pr][0];
        p1[c][pr][1] = p1o[c][pr][1];
        p1[c][pr][2] = __shfl_down(p1o[c][pr][0], 1);
    }

    // conv2 -> pool (raw max) -> leaky -> store
    if (x < 59) {
        float* xrow = xbuf + (size_t)(r * BS + b) * XDIM + (size_t)(t * 2) * 3481
                      + y * 59 + x;
        #pragma unroll
        for (int c2 = 0; c2 < 2; ++c2) {
            float mx = -3.4e38f;
            #pragma unroll
            for (int a2 = 0; a2 < 2; ++a2)
            #pragma unroll
            for (int b2i = 0; b2i < 2; ++b2i) {
                float acc = b2r[c2];
                #pragma unroll
                for (int c1 = 0; c1 < 2; ++c1)
                #pragma unroll
                for (int du = 0; du < 2; ++du)
                #pragma unroll
                for (int dv = 0; dv < 2; ++dv)
                    acc += w2r[((c2 * 2 + c1) * 2 + du) * 2 + dv]
                         * p1[c1][a2 + du][b2i + dv];
                mx = fmaxf(mx, acc);
            }
            xrow[(size_t)c2 * 3481] = leaky(mx);
        }
    }
}

// ---------------------------------------------------------------------------
// fc1 as tiled split-K GEMM:  psum[kc][row][n] = sum_{k in chunk kc} X[row][k]*W1[n][k]
// Grid: (NKCH, 8 m-tiles). Block 256 thr: tile M=32, N=64(60 used), K=128.
// ---------------------------------------------------------------------------
__global__ __launch_bounds__(256) void gemm_fc1_kernel(
    const float* __restrict__ xbuf, const float* __restrict__ fc1w,
    float* __restrict__ psum)
{
    const int kc   = blockIdx.x;
    const int mt   = blockIdx.y;
    const int tid  = threadIdx.x;
    const int kbase = kc * KC;
    const int rem   = min(KC, XDIM - kbase);   // 7 on last chunk
    const int row0  = mt * 32;

    __shared__ float4 X4[32][33];   // [m][k4], row stride 132 floats (2-way banks: free)
    __shared__ float4 W4[64][33];   // [n][k4]

    float* Xs = reinterpret_cast<float*>(&X4[0][0]);
    float* Ws = reinterpret_cast<float*>(&W4[0][0]);

    for (int idx = tid; idx < 32 * KC; idx += 256) {
        const int m = idx >> 7, k = idx & 127;
        Xs[m * 132 + k] = (k < rem) ? xbuf[(size_t)(row0 + m) * XDIM + kbase + k] : 0.f;
    }
    for (int idx = tid; idx < 64 * KC; idx += 256) {
        const int n = idx >> 7, k = idx & 127;
        Ws[n * 132 + k] = (n < 60 && k < rem) ? fc1w[(size_t)n * XDIM + kbase + k] : 0.f;
    }
    __syncthreads();

    const int ty = tid >> 4, tx = tid & 15;
    const int m0 = ty * 2;

    float acc[2][4];
    #pragma unroll
    for (int i = 0; i < 2; ++i)
    #pragma unroll
    for (int j = 0; j < 4; ++j) acc[i][j] = 0.f;

    #pragma unroll 4
    for (int k4 = 0; k4 < 32; ++k4) {
        const float4 xa = X4[m0][k4];
        const float4 xb = X4[m0 + 1][k4];
        #pragma unroll
        for (int j = 0; j < 4; ++j) {
            const float4 w = W4[tx + 16 * j][k4];
            acc[0][j] += xa.x * w.x + xa.y * w.y + xa.z * w.z + xa.w * w.w;
            acc[1][j] += xb.x * w.x + xb.y * w.y + xb.z * w.z + xb.w * w.w;
        }
    }

    float* po = psum + ((size_t)kc * 256 + row0) * 64;
    #pragma unroll
    for (int i = 0; i < 2; ++i)
    #pragma unroll
    for (int j = 0; j < 4; ++j)
        po[(size_t)(m0 + i) * 64 + tx + 16 * j] = acc[i][j];
}

// ---------------------------------------------------------------------------
// Tail: reduce psum over chunks, bias+leaky, fc2, fc3, * nu, sum over r.
// Grid 128 (one block per b), 512 threads = (rh 2) x (kq 4) x (n 64):
// each thread sums ~28 chunks (vs 111 serial) then LDS-reduces over kq.
// Deterministic (no atomics).
// ---------------------------------------------------------------------------
__global__ __launch_bounds__(512) void fc_tail_kernel(
    const float* __restrict__ psum,
    const float* __restrict__ fc1b,
    const float* __restrict__ fc2w, const float* __restrict__ fc2b,
    const float* __restrict__ fc3w, const float* __restrict__ fc3b,
    const float* __restrict__ nu, float* __restrict__ out)
{
    const int b = blockIdx.x;
    const int tid = threadIdx.x;
    const int n  = tid & 63;
    const int kq = (tid >> 6) & 3;
    const int rh = tid >> 8;

    __shared__ float red[2][4][64];
    __shared__ float y1s[2][64];
    __shared__ float y2s[2][30];

    const int row = rh * 128 + b;
    float s = 0.f;
    for (int kcc = kq; kcc < NKCH; kcc += 4)
        s += psum[((size_t)kcc * 256 + row) * 64 + n];
    red[rh][kq][n] = s;
    __syncthreads();

    if (kq == 0) {
        float t = red[rh][0][n] + red[rh][1][n] + red[rh][2][n] + red[rh][3][n];
        y1s[rh][n] = (n < 60) ? leaky(t + fc1b[n]) : 0.f;
    }
    __syncthreads();

    if (kq == 0 && n < 30) {
        float a2 = fc2b[n];
        const float* wr = fc2w + n * 60;
        #pragma unroll
        for (int k = 0; k < 60; ++k) a2 += wr[k] * y1s[rh][k];
        y2s[rh][n] = leaky(a2);
    }
    __syncthreads();

    if (tid == 0) {
        float acc_out = 0.f;
        #pragma unroll
        for (int r = 0; r < 2; ++r) {
            float a3 = fc3b[0];
            #pragma unroll
            for (int k = 0; k < 30; ++k) a3 += fc3w[k] * y2s[r][k];
            acc_out += a3 * nu[b * 2 + r];
        }
        out[b] = acc_out;
    }
}

extern "C" void kernel_launch(void* const* d_in, const int* in_sizes, int n_in,
                              void* d_out, int out_size, void* d_ws, size_t ws_size,
                              hipStream_t stream)
{
    const float* xyz   = (const float*)d_in[0];
    const float* cn    = (const float*)d_in[1];
    const float* edisp = (const float*)d_in[2];
    const float* ovlp  = (const float*)d_in[3];
    const float* h0    = (const float*)d_in[4];
    const float* egfn1 = (const float*)d_in[5];
    const float* nu    = (const float*)d_in[6];
    const float* We1   = (const float*)d_in[7];
    const float* be1   = (const float*)d_in[8];
    const float* We2   = (const float*)d_in[9];
    const float* be2   = (const float*)d_in[10];
    // d_in[11..15] = Wc1,bc1,Wc2,bc2,coors_scale: dead code (coors_out discarded)
    const float* Wn1   = (const float*)d_in[16];
    const float* bn1   = (const float*)d_in[17];
    const float* Wn2   = (const float*)d_in[18];
    const float* bn2   = (const float*)d_in[19];
    const float* c1w   = (const float*)d_in[20];
    const float* c1b   = (const float*)d_in[21];
    const float* c2w   = (const float*)d_in[22];
    const float* c2b   = (const float*)d_in[23];
    const float* fc1w  = (const float*)d_in[24];
    const float* fc1b  = (const float*)d_in[25];
    const float* fc2w  = (const float*)d_in[26];
    const float* fc2b  = (const float*)d_in[27];
    const float* fc3w  = (const float*)d_in[28];
    const float* fc3b  = (const float*)d_in[29];

    float* xbuf = (float*)d_ws;                         // 256 x 14087 f32 = 14.43 MB
    float* psum = (float*)((char*)d_ws + 14425088);     // 111 x 256 x 64 f32 = 7.27 MB
    float* out  = (float*)d_out;

    hipLaunchKernelGGL(egnn_kernel, dim3(256), dim3(512), 0, stream,
                       xyz, cn, edisp, egfn1, We1, be1, We2, be2,
                       Wn1, bn1, Wn2, bn2, xbuf);
    hipLaunchKernelGGL(conv_kernel, dim3(2 * 2 * BS * 15), dim3(256), 0, stream,
                       ovlp, h0, c1w, c1b, c2w, c2b, xbuf);
    hipLaunchKernelGGL(gemm_fc1_kernel, dim3(NKCH, 8), dim3(256), 0, stream,
                       xbuf, fc1w, psum);
    hipLaunchKernelGGL(fc_tail_kernel, dim3(128), dim3(512), 0, stream,
                       psum, fc1b, fc2w, fc2b, fc3w, fc3b, nu, out);
}

// Round 7
// 248.697 us; speedup vs baseline: 1.1453x; 1.0953x over previous
//
#include <hip/hip_runtime.h>
#include <hip/hip_bf16.h>

#define XDIM 14087   // 4*3481 conv + 162 atm + 1 egfn1
#define XPAD 14208   // 111*128; xbuf row stride, pad cols zeroed each launch
#define NATM 81
#define BS   128
#define KC   128          // K-chunk for fc1 GEMM
#define NKCH 111          // XPAD / KC

__device__ __forceinline__ float fast_rcp(float x) {
    return __builtin_amdgcn_rcpf(x);
}
__device__ __forceinline__ float silu(float z) {
    return z * fast_rcp(1.f + __expf(-z));
}
__device__ __forceinline__ float leaky(float z) {
    return (z > 0.f) ? z : 0.01f * z;
}

// async global->LDS, 16B per lane, dst = uniform base + lane*16 (linear)
__device__ __forceinline__ void gload_lds16(const float* g, float* l) {
    __builtin_amdgcn_global_load_lds(
        (const __attribute__((address_space(1))) unsigned int*)g,
        (__attribute__((address_space(3))) unsigned int*)l, 16, 0, 0);
}

// ---------------------------------------------------------------------------
// Zero xbuf pad columns [XDIM, XPAD) — ws is re-poisoned 0xAA before each call.
// ---------------------------------------------------------------------------
__global__ __launch_bounds__(128) void padzero_kernel(float* __restrict__ xbuf) {
    const int row = blockIdx.x;
    const int tid = threadIdx.x;
    if (tid < XPAD - XDIM)
        xbuf[(size_t)row * XPAD + XDIM + tid] = 0.f;
}

// ---------------------------------------------------------------------------
// EGNN: one block per (r,b). 486 active threads = 81 i-nodes x 3 j-parts x 2 k2-halves.
// ---------------------------------------------------------------------------
__global__ __launch_bounds__(512) void egnn_kernel(
    const float* __restrict__ xyz, const float* __restrict__ cn,
    const float* __restrict__ edisp, const float* __restrict__ egfn1,
    const float* __restrict__ We1, const float* __restrict__ be1,
    const float* __restrict__ We2, const float* __restrict__ be2,
    const float* __restrict__ Wn1, const float* __restrict__ bn1,
    const float* __restrict__ Wn2, const float* __restrict__ bn2,
    float* __restrict__ xbuf)
{
    const int bid = blockIdx.x;      // r*128 + b
    const int tid = threadIdx.x;

    __shared__ float sc[NATM][3];
    __shared__ float sf[NATM][2];
    __shared__ float sai[NATM][10];
    __shared__ float sbj[NATM][10];
    __shared__ float sW2[160];
    __shared__ float sbe2[16];
    __shared__ float sw5[10];
    __shared__ float sWn1[72];
    __shared__ float sbn1[4];
    __shared__ float sWn2[8];
    __shared__ float sbn2[2];
    __shared__ float smp[3][NATM][17];   // padded stride 17: conflict-free

    const float* xb = xyz + (size_t)bid * NATM * 3;
    for (int idx = tid; idx < NATM * 3; idx += 512) sc[idx / 3][idx % 3] = xb[idx];
    if (tid < NATM) {
        const float f0 = cn[(size_t)bid * NATM + tid];
        const float f1 = edisp[(size_t)bid * NATM + tid];
        sf[tid][0] = f0; sf[tid][1] = f1;
        #pragma unroll
        for (int k = 0; k < 10; ++k) {
            sai[tid][k] = be1[k] + We1[k * 5 + 0] * f0 + We1[k * 5 + 1] * f1;
            sbj[tid][k] =          We1[k * 5 + 2] * f0 + We1[k * 5 + 3] * f1;
        }
    }
    if (tid < 160) sW2[tid] = We2[tid];
    if (tid < 16)  sbe2[tid] = be2[tid];
    if (tid < 10)  sw5[tid] = We1[tid * 5 + 4];
    if (tid < 72)  sWn1[tid] = Wn1[tid];
    if (tid < 4)   sbn1[tid] = bn1[tid];
    if (tid < 8)   sWn2[tid] = Wn2[tid];
    if (tid < 2)   sbn2[tid] = bn2[tid];
    __syncthreads();

    if (tid < 486) {
        const int i    = tid % 81;
        const int part = (tid / 81) % 3;
        const int half = tid / 243;

        float W2r[80];
        #pragma unroll
        for (int q = 0; q < 80; ++q) W2r[q] = sW2[half * 80 + q];
        float be2r[8];
        #pragma unroll
        for (int q = 0; q < 8; ++q) be2r[q] = sbe2[half * 8 + q];
        float w5r[10];
        #pragma unroll
        for (int k = 0; k < 10; ++k) w5r[k] = sw5[k];
        float air[10];
        #pragma unroll
        for (int k = 0; k < 10; ++k) air[k] = sai[i][k];
        const float ci0 = sc[i][0], ci1 = sc[i][1], ci2 = sc[i][2];

        float macc[8];
        #pragma unroll
        for (int q = 0; q < 8; ++q) macc[q] = 0.f;

        const int j0 = part * 27;
        for (int j = j0; j < j0 + 27; ++j) {
            const float dx = ci0 - sc[j][0];
            const float dy = ci1 - sc[j][1];
            const float dz = ci2 - sc[j][2];
            const float rd = dx * dx + dy * dy + dz * dz;
            float h[10];
            #pragma unroll
            for (int k = 0; k < 10; ++k) {
                const float z = air[k] + sbj[j][k] + w5r[k] * rd;
                h[k] = silu(z);
            }
            #pragma unroll
            for (int q = 0; q < 8; ++q) {
                float z = be2r[q];
                #pragma unroll
                for (int k = 0; k < 10; ++k) z += W2r[q * 10 + k] * h[k];
                macc[q] += silu(z);
            }
        }
        #pragma unroll
        for (int q = 0; q < 8; ++q) smp[part][i][half * 8 + q] = macc[q];
    }
    __syncthreads();

    if (tid < NATM) {
        float mi[16];
        #pragma unroll
        for (int q = 0; q < 16; ++q)
            mi[q] = smp[0][tid][q] + smp[1][tid][q] + smp[2][tid][q];
        const float f0 = sf[tid][0], f1 = sf[tid][1];
        float n1[4];
        #pragma unroll
        for (int k = 0; k < 4; ++k) {
            float z = sbn1[k] + sWn1[k * 18 + 0] * f0 + sWn1[k * 18 + 1] * f1;
            #pragma unroll
            for (int q = 0; q < 16; ++q) z += sWn1[k * 18 + 2 + q] * mi[q];
            n1[k] = silu(z);
        }
        float* xrow = xbuf + (size_t)bid * XPAD + 13924 + tid * 2;
        #pragma unroll
        for (int c = 0; c < 2; ++c) {
            float z = sbn2[c] + (c ? f1 : f0);
            #pragma unroll
            for (int k = 0; k < 4; ++k) z += sWn2[c * 4 + k] * n1[k];
            xrow[c] = z;
        }
    }
    if (tid == 0) xbuf[(size_t)bid * XPAD + 14086] = egfn1[bid];
}

// ---------------------------------------------------------------------------
// Fused conv block, v5: wave = TWO output rows (11 input rows vs 2x7),
// lane = one output col. Loads: 11 float4/lane, 5th column imported via
// __shfl_down of neighbor's .x. Pool1 col sharing via shfl. leaky folded
// through both max-pools (exact, monotone). Input rows clamped at 239.
// ---------------------------------------------------------------------------
__global__ __launch_bounds__(256) void conv_kernel(
    const float* __restrict__ ovlp, const float* __restrict__ h0,
    const float* __restrict__ w1, const float* __restrict__ b1,
    const float* __restrict__ w2, const float* __restrict__ b2,
    float* __restrict__ xbuf)
{
    const int bid   = blockIdx.x;
    const int strip = bid & 7;           // 8 strips x 8 rows = 64 >= 59
    const int img   = bid >> 3;          // r*256 + t*128 + b
    const int b     = img & 127;
    const int t     = (img >> 7) & 1;
    const int r     = img >> 8;
    const int tid   = threadIdx.x;

    const int wv = tid >> 6;
    const int l  = tid & 63;
    const int y0 = strip * 8 + wv * 2;   // first of 2 output rows (wave-uniform)
    if (y0 >= 59) return;
    const int x  = l;
    const int xc = (x < 59) ? x : 59;    // lanes 59..63 duplicate col block 59

    const float* src = (t ? h0 : ovlp) + (size_t)(r * BS + b) * 57600;

    float w1r[8], w2r[16], b1r[2], b2r[2];
    #pragma unroll
    for (int k = 0; k < 8; ++k) w1r[k] = w1[k];
    #pragma unroll
    for (int k = 0; k < 16; ++k) w2r[k] = w2[k];
    b1r[0] = b1[0]; b1r[1] = b1[1];
    b2r[0] = b2[0]; b2r[1] = b2[1];

    // 11x5 patch: rows 4y0..4y0+10 (clamped), cols 4xc..4xc+4
    float P[11][5];
    #pragma unroll
    for (int rr = 0; rr < 11; ++rr) {
        int gr = 4 * y0 + rr;
        if (gr > 239) gr = 239;          // feeds only masked output row 59
        const float4 a = *reinterpret_cast<const float4*>(src + gr * 240 + 4 * xc);
        P[rr][0] = a.x; P[rr][1] = a.y; P[rr][2] = a.z; P[rr][3] = a.w;
    }
    #pragma unroll
    for (int rr = 0; rr < 11; ++rr)
        P[rr][4] = __shfl_down(P[rr][0], 1);   // col 4x+4 from lane x+1

    // conv1 -> pool (raw max) -> leaky: own pool cols {2x,2x+1}, 5 pool rows
    float p1o[2][5][2];
    #pragma unroll
    for (int c = 0; c < 2; ++c) {
        const float wa = w1r[c * 4 + 0], wb = w1r[c * 4 + 1];
        const float wc = w1r[c * 4 + 2], wd = w1r[c * 4 + 3];
        const float bb = b1r[c];
        #pragma unroll
        for (int pr = 0; pr < 5; ++pr)
        #pragma unroll
        for (int pc = 0; pc < 2; ++pc) {
            float mx = -3.4e38f;
            #pragma unroll
            for (int s = 0; s < 2; ++s)
            #pragma unroll
            for (int tt = 0; tt < 2; ++tt) {
                const int u = 2 * pr + s, v = 2 * pc + tt;
                const float raw = fmaf(wa, P[u][v], fmaf(wb, P[u][v + 1],
                                  fmaf(wc, P[u + 1][v], fmaf(wd, P[u + 1][v + 1], bb))));
                mx = fmaxf(mx, raw);
            }
            p1o[c][pr][pc] = leaky(mx);
        }
    }

    // pool col 2x+2 from lane x+1
    float p1[2][5][3];
    #pragma unroll
    for (int c = 0; c < 2; ++c)
    #pragma unroll
    for (int pr = 0; pr < 5; ++pr) {
        p1[c][pr][0] = p1o[c][pr][0];
        p1[c][pr][1] = p1o[c][pr][1];
        p1[c][pr][2] = __shfl_down(p1o[c][pr][0], 1);
    }

    // conv2 -> pool (raw max) -> leaky -> store, for 2 output rows
    #pragma unroll
    for (int oy = 0; oy < 2; ++oy) {
        const int y = y0 + oy;
        if (y >= 59) break;              // wave-uniform
        if (x < 59) {
            float* xrow = xbuf + (size_t)(r * BS + b) * XPAD + (size_t)(t * 2) * 3481
                          + y * 59 + x;
            #pragma unroll
            for (int c2 = 0; c2 < 2; ++c2) {
                float mx = -3.4e38f;
                #pragma unroll
                for (int a2 = 0; a2 < 2; ++a2)
                #pragma unroll
                for (int b2i = 0; b2i < 2; ++b2i) {
                    float acc = b2r[c2];
                    #pragma unroll
                    for (int c1 = 0; c1 < 2; ++c1)
                    #pragma unroll
                    for (int du = 0; du < 2; ++du)
                    #pragma unroll
                    for (int dv = 0; dv < 2; ++dv)
                        acc += w2r[((c2 * 2 + c1) * 2 + du) * 2 + dv]
                             * p1[c1][2 * oy + a2 + du][b2i + dv];
                    mx = fmaxf(mx, acc);
                }
                xrow[(size_t)c2 * 3481] = leaky(mx);
            }
        }
    }
}

// ---------------------------------------------------------------------------
// fc1 split-K GEMM v2: async global_load_lds staging, linear LDS dest with
// XOR-swizzled SOURCE addresses and matching swizzled reads (rule #21).
// Tail-chunk fix: W row 59's k4=1 chunk (k=14084..14086 valid) would read 4B
// past fc1w's end, so it's clamped at stage time and PATCHED from valid
// scalar reads after the barrier (only blocks kc==NKCH-1; uniform branch).
// All other clamped chunks pair with X-pad zeros (contribution 0).
// ---------------------------------------------------------------------------
__global__ __launch_bounds__(256) void gemm_fc1_kernel(
    const float* __restrict__ xbuf, const float* __restrict__ fc1w,
    float* __restrict__ psum)
{
    const int kc   = blockIdx.x;
    const int mt   = blockIdx.y;
    const int tid  = threadIdx.x;
    const int w    = tid >> 6;
    const int l    = tid & 63;
    const int kbase = kc * KC;
    const int row0  = mt * 32;

    __shared__ __align__(16) float Xs[32 * 128];   // elem (m,k4,e) at m*128+(k4^m)*4+e
    __shared__ __align__(16) float Ws[64 * 128];   // elem (n,k4,e) at n*128+(k4^(n&31))*4+e

    // stage X: 16 x 1KB async instrs (wave w issues 4)
    const int ml  = l >> 5;
    const int k4s = l & 31;
    #pragma unroll
    for (int i = 0; i < 4; ++i) {
        const int s  = w * 4 + i;
        const int m  = s * 2 + ml;
        const int k4 = k4s ^ (m & 31);
        gload_lds16(xbuf + (size_t)(row0 + m) * XPAD + kbase + k4 * 4,
                    Xs + s * 256);
    }
    // stage W: 32 x 1KB async instrs (wave w issues 8)
    const float* gmax = fc1w + ((size_t)60 * XDIM - 4);  // last aligned f4 in-bounds
    #pragma unroll
    for (int i = 0; i < 8; ++i) {
        const int s  = w * 8 + i;
        const int n  = s * 2 + ml;
        const int k4 = k4s ^ (n & 31);
        const float* g = fc1w + (size_t)n * XDIM + kbase + k4 * 4;
        if (g > gmax) g = gmax;          // n>=60 rows + tail-chunk OOB: clamp
        gload_lds16(g, Ws + s * 256);
    }
    __syncthreads();   // drains vmcnt(0) (compiler emits full waitcnt before barrier)

    if (kc == NKCH - 1) {
        // patch (n=59, k4=1): LDS float offset 59*128 + (1^27)*4 = 7656
        if (tid < 3) Ws[7656 + tid] = fc1w[(size_t)59 * XDIM + 14084 + tid];
        if (tid == 3) Ws[7659] = 0.f;    // k=14087 pairs with X pad zero anyway
        __syncthreads();
    }

    const int ty = tid >> 4, tx = tid & 15;
    const int m0 = ty * 2;
    const float4* X4 = reinterpret_cast<const float4*>(Xs);
    const float4* W4 = reinterpret_cast<const float4*>(Ws);

    float acc[2][4];
    #pragma unroll
    for (int i = 0; i < 2; ++i)
    #pragma unroll
    for (int j = 0; j < 4; ++j) acc[i][j] = 0.f;

    #pragma unroll 4
    for (int k4 = 0; k4 < 32; ++k4) {
        const float4 xa = X4[m0 * 32 + (k4 ^ m0)];
        const float4 xb = X4[(m0 + 1) * 32 + (k4 ^ (m0 + 1))];
        #pragma unroll
        for (int j = 0; j < 4; ++j) {
            const int n = tx + 16 * j;
            const float4 wv4 = W4[n * 32 + (k4 ^ (n & 31))];
            acc[0][j] += xa.x * wv4.x + xa.y * wv4.y + xa.z * wv4.z + xa.w * wv4.w;
            acc[1][j] += xb.x * wv4.x + xb.y * wv4.y + xb.z * wv4.z + xb.w * wv4.w;
        }
    }

    float* po = psum + ((size_t)kc * 256 + row0) * 64;
    #pragma unroll
    for (int i = 0; i < 2; ++i)
    #pragma unroll
    for (int j = 0; j < 4; ++j)
        po[(size_t)(m0 + i) * 64 + tx + 16 * j] = acc[i][j];
}

// ---------------------------------------------------------------------------
// Tail: reduce psum over chunks, bias+leaky, fc2, fc3, * nu, sum over r.
// Grid 128, 512 thr = (rh 2) x (kq 4) x (n 64). Deterministic.
// Cols 60..63 of psum hold garbage (clamped W rows) — masked here.
// ---------------------------------------------------------------------------
__global__ __launch_bounds__(512) void fc_tail_kernel(
    const float* __restrict__ psum,
    const float* __restrict__ fc1b,
    const float* __restrict__ fc2w, const float* __restrict__ fc2b,
    const float* __restrict__ fc3w, const float* __restrict__ fc3b,
    const float* __restrict__ nu, float* __restrict__ out)
{
    const int b = blockIdx.x;
    const int tid = threadIdx.x;
    const int n  = tid & 63;
    const int kq = (tid >> 6) & 3;
    const int rh = tid >> 8;

    __shared__ float red[2][4][64];
    __shared__ float y1s[2][64];
    __shared__ float y2s[2][30];

    const int row = rh * 128 + b;
    float s = 0.f;
    for (int kcc = kq; kcc < NKCH; kcc += 4)
        s += psum[((size_t)kcc * 256 + row) * 64 + n];
    red[rh][kq][n] = s;
    __syncthreads();

    if (kq == 0) {
        float tt = red[rh][0][n] + red[rh][1][n] + red[rh][2][n] + red[rh][3][n];
        y1s[rh][n] = (n < 60) ? leaky(tt + fc1b[n]) : 0.f;
    }
    __syncthreads();

    if (kq == 0 && n < 30) {
        float a2 = fc2b[n];
        const float* wr = fc2w + n * 60;
        #pragma unroll
        for (int k = 0; k < 60; ++k) a2 += wr[k] * y1s[rh][k];
        y2s[rh][n] = leaky(a2);
    }
    __syncthreads();

    if (tid == 0) {
        float acc_out = 0.f;
        #pragma unroll
        for (int r = 0; r < 2; ++r) {
            float a3 = fc3b[0];
            #pragma unroll
            for (int k = 0; k < 30; ++k) a3 += fc3w[k] * y2s[r][k];
            acc_out += a3 * nu[b * 2 + r];
        }
        out[b] = acc_out;
    }
}

extern "C" void kernel_launch(void* const* d_in, const int* in_sizes, int n_in,
                              void* d_out, int out_size, void* d_ws, size_t ws_size,
                              hipStream_t stream)
{
    const float* xyz   = (const float*)d_in[0];
    const float* cn    = (const float*)d_in[1];
    const float* edisp = (const float*)d_in[2];
    const float* ovlp  = (const float*)d_in[3];
    const float* h0    = (const float*)d_in[4];
    const float* egfn1 = (const float*)d_in[5];
    const float* nu    = (const float*)d_in[6];
    const float* We1   = (const float*)d_in[7];
    const float* be1   = (const float*)d_in[8];
    const float* We2   = (const float*)d_in[9];
    const float* be2   = (const float*)d_in[10];
    // d_in[11..15] = Wc1,bc1,Wc2,bc2,coors_scale: dead code (coors_out discarded)
    const float* Wn1   = (const float*)d_in[16];
    const float* bn1   = (const float*)d_in[17];
    const float* Wn2   = (const float*)d_in[18];
    const float* bn2   = (const float*)d_in[19];
    const float* c1w   = (const float*)d_in[20];
    const float* c1b   = (const float*)d_in[21];
    const float* c2w   = (const float*)d_in[22];
    const float* c2b   = (const float*)d_in[23];
    const float* fc1w  = (const float*)d_in[24];
    const float* fc1b  = (const float*)d_in[25];
    const float* fc2w  = (const float*)d_in[26];
    const float* fc2b  = (const float*)d_in[27];
    const float* fc3w  = (const float*)d_in[28];
    const float* fc3b  = (const float*)d_in[29];

    float* xbuf = (float*)d_ws;                           // 256 x 14208 f32 = 14.55 MB
    float* psum = (float*)((char*)d_ws + (size_t)256 * XPAD * 4);  // 111x256x64 f32 = 7.27 MB
    float* out  = (float*)d_out;

    hipLaunchKernelGGL(padzero_kernel, dim3(256), dim3(128), 0, stream, xbuf);
    hipLaunchKernelGGL(egnn_kernel, dim3(256), dim3(512), 0, stream,
                       xyz, cn, edisp, egfn1, We1, be1, We2, be2,
                       Wn1, bn1, Wn2, bn2, xbuf);
    hipLaunchKernelGGL(conv_kernel, dim3(512 * 8), dim3(256), 0, stream,
                       ovlp, h0, c1w, c1b, c2w, c2b, xbuf);
    hipLaunchKernelGGL(gemm_fc1_kernel, dim3(NKCH, 8), dim3(256), 0, stream,
                       xbuf, fc1w, psum);
    hipLaunchKernelGGL(fc_tail_kernel, dim3(128), dim3(512), 0, stream,
                       psum, fc1b, fc2w, fc2b, fc3w, fc3b, nu, out);
}

// Round 8
// 247.298 us; speedup vs baseline: 1.1518x; 1.0057x over previous
//
#include <hip/hip_runtime.h>
#include <hip/hip_bf16.h>

#define XDIM 14087   // 4*3481 conv + 162 atm + 1 egfn1
#define XPAD 14208   // 111*128; xbuf row stride, pad cols zeroed each launch
#define NATM 81
#define BS   128
#define KC   128          // K-chunk for fc1 GEMM
#define NKCH 111          // XPAD / KC

__device__ __forceinline__ float fast_rcp(float x) {
    return __builtin_amdgcn_rcpf(x);
}
__device__ __forceinline__ float silu(float z) {
    return z * fast_rcp(1.f + __expf(-z));
}
__device__ __forceinline__ float leaky(float z) {
    return (z > 0.f) ? z : 0.01f * z;
}

// async global->LDS, 16B per lane, dst = uniform base + lane*16 (linear)
__device__ __forceinline__ void gload_lds16(const float* g, float* l) {
    __builtin_amdgcn_global_load_lds(
        (const __attribute__((address_space(1))) unsigned int*)g,
        (__attribute__((address_space(3))) unsigned int*)l, 16, 0, 0);
}

// ---------------------------------------------------------------------------
// Zero xbuf pad columns [XDIM, XPAD) — ws is re-poisoned 0xAA before each call.
// ---------------------------------------------------------------------------
__global__ __launch_bounds__(128) void padzero_kernel(float* __restrict__ xbuf) {
    const int row = blockIdx.x;
    const int tid = threadIdx.x;
    if (tid < XPAD - XDIM)
        xbuf[(size_t)row * XPAD + XDIM + tid] = 0.f;
}

// ---------------------------------------------------------------------------
// EGNN: one block per (r,b). 486 active threads = 81 i-nodes x 3 j-parts x 2 k2-halves.
// ---------------------------------------------------------------------------
__global__ __launch_bounds__(512) void egnn_kernel(
    const float* __restrict__ xyz, const float* __restrict__ cn,
    const float* __restrict__ edisp, const float* __restrict__ egfn1,
    const float* __restrict__ We1, const float* __restrict__ be1,
    const float* __restrict__ We2, const float* __restrict__ be2,
    const float* __restrict__ Wn1, const float* __restrict__ bn1,
    const float* __restrict__ Wn2, const float* __restrict__ bn2,
    float* __restrict__ xbuf)
{
    const int bid = blockIdx.x;      // r*128 + b
    const int tid = threadIdx.x;

    __shared__ float sc[NATM][3];
    __shared__ float sf[NATM][2];
    __shared__ float sai[NATM][10];
    __shared__ float sbj[NATM][10];
    __shared__ float sW2[160];
    __shared__ float sbe2[16];
    __shared__ float sw5[10];
    __shared__ float sWn1[72];
    __shared__ float sbn1[4];
    __shared__ float sWn2[8];
    __shared__ float sbn2[2];
    __shared__ float smp[3][NATM][17];   // padded stride 17: conflict-free

    const float* xb = xyz + (size_t)bid * NATM * 3;
    for (int idx = tid; idx < NATM * 3; idx += 512) sc[idx / 3][idx % 3] = xb[idx];
    if (tid < NATM) {
        const float f0 = cn[(size_t)bid * NATM + tid];
        const float f1 = edisp[(size_t)bid * NATM + tid];
        sf[tid][0] = f0; sf[tid][1] = f1;
        #pragma unroll
        for (int k = 0; k < 10; ++k) {
            sai[tid][k] = be1[k] + We1[k * 5 + 0] * f0 + We1[k * 5 + 1] * f1;
            sbj[tid][k] =          We1[k * 5 + 2] * f0 + We1[k * 5 + 3] * f1;
        }
    }
    if (tid < 160) sW2[tid] = We2[tid];
    if (tid < 16)  sbe2[tid] = be2[tid];
    if (tid < 10)  sw5[tid] = We1[tid * 5 + 4];
    if (tid < 72)  sWn1[tid] = Wn1[tid];
    if (tid < 4)   sbn1[tid] = bn1[tid];
    if (tid < 8)   sWn2[tid] = Wn2[tid];
    if (tid < 2)   sbn2[tid] = bn2[tid];
    __syncthreads();

    if (tid < 486) {
        const int i    = tid % 81;
        const int part = (tid / 81) % 3;
        const int half = tid / 243;

        float W2r[80];
        #pragma unroll
        for (int q = 0; q < 80; ++q) W2r[q] = sW2[half * 80 + q];
        float be2r[8];
        #pragma unroll
        for (int q = 0; q < 8; ++q) be2r[q] = sbe2[half * 8 + q];
        float w5r[10];
        #pragma unroll
        for (int k = 0; k < 10; ++k) w5r[k] = sw5[k];
        float air[10];
        #pragma unroll
        for (int k = 0; k < 10; ++k) air[k] = sai[i][k];
        const float ci0 = sc[i][0], ci1 = sc[i][1], ci2 = sc[i][2];

        float macc[8];
        #pragma unroll
        for (int q = 0; q < 8; ++q) macc[q] = 0.f;

        const int j0 = part * 27;
        for (int j = j0; j < j0 + 27; ++j) {
            const float dx = ci0 - sc[j][0];
            const float dy = ci1 - sc[j][1];
            const float dz = ci2 - sc[j][2];
            const float rd = dx * dx + dy * dy + dz * dz;
            float h[10];
            #pragma unroll
            for (int k = 0; k < 10; ++k) {
                const float z = air[k] + sbj[j][k] + w5r[k] * rd;
                h[k] = silu(z);
            }
            #pragma unroll
            for (int q = 0; q < 8; ++q) {
                float z = be2r[q];
                #pragma unroll
                for (int k = 0; k < 10; ++k) z += W2r[q * 10 + k] * h[k];
                macc[q] += silu(z);
            }
        }
        #pragma unroll
        for (int q = 0; q < 8; ++q) smp[part][i][half * 8 + q] = macc[q];
    }
    __syncthreads();

    if (tid < NATM) {
        float mi[16];
        #pragma unroll
        for (int q = 0; q < 16; ++q)
            mi[q] = smp[0][tid][q] + smp[1][tid][q] + smp[2][tid][q];
        const float f0 = sf[tid][0], f1 = sf[tid][1];
        float n1[4];
        #pragma unroll
        for (int k = 0; k < 4; ++k) {
            float z = sbn1[k] + sWn1[k * 18 + 0] * f0 + sWn1[k * 18 + 1] * f1;
            #pragma unroll
            for (int q = 0; q < 16; ++q) z += sWn1[k * 18 + 2 + q] * mi[q];
            n1[k] = silu(z);
        }
        float* xrow = xbuf + (size_t)bid * XPAD + 13924 + tid * 2;
        #pragma unroll
        for (int c = 0; c < 2; ++c) {
            float z = sbn2[c] + (c ? f1 : f0);
            #pragma unroll
            for (int k = 0; k < 4; ++k) z += sWn2[c * 4 + k] * n1[k];
            xrow[c] = z;
        }
    }
    if (tid == 0) xbuf[(size_t)bid * XPAD + 14086] = egfn1[bid];
}

// ---------------------------------------------------------------------------
// Fused conv block, v5: wave = TWO output rows (11 input rows), lane = one
// output col. 11 float4/lane; 5th column via __shfl_down of neighbor's .x.
// Pool1 col sharing via shfl. leaky folded through both max-pools (exact).
// ---------------------------------------------------------------------------
__global__ __launch_bounds__(256) void conv_kernel(
    const float* __restrict__ ovlp, const float* __restrict__ h0,
    const float* __restrict__ w1, const float* __restrict__ b1,
    const float* __restrict__ w2, const float* __restrict__ b2,
    float* __restrict__ xbuf)
{
    const int bid   = blockIdx.x;
    const int strip = bid & 7;           // 8 strips x 8 rows = 64 >= 59
    const int img   = bid >> 3;          // r*256 + t*128 + b
    const int b     = img & 127;
    const int t     = (img >> 7) & 1;
    const int r     = img >> 8;
    const int tid   = threadIdx.x;

    const int wv = tid >> 6;
    const int l  = tid & 63;
    const int y0 = strip * 8 + wv * 2;   // first of 2 output rows (wave-uniform)
    if (y0 >= 59) return;
    const int x  = l;
    const int xc = (x < 59) ? x : 59;    // lanes 59..63 duplicate col block 59

    const float* src = (t ? h0 : ovlp) + (size_t)(r * BS + b) * 57600;

    float w1r[8], w2r[16], b1r[2], b2r[2];
    #pragma unroll
    for (int k = 0; k < 8; ++k) w1r[k] = w1[k];
    #pragma unroll
    for (int k = 0; k < 16; ++k) w2r[k] = w2[k];
    b1r[0] = b1[0]; b1r[1] = b1[1];
    b2r[0] = b2[0]; b2r[1] = b2[1];

    // 11x5 patch: rows 4y0..4y0+10 (clamped), cols 4xc..4xc+4
    float P[11][5];
    #pragma unroll
    for (int rr = 0; rr < 11; ++rr) {
        int gr = 4 * y0 + rr;
        if (gr > 239) gr = 239;          // feeds only masked output row 59
        const float4 a = *reinterpret_cast<const float4*>(src + gr * 240 + 4 * xc);
        P[rr][0] = a.x; P[rr][1] = a.y; P[rr][2] = a.z; P[rr][3] = a.w;
    }
    #pragma unroll
    for (int rr = 0; rr < 11; ++rr)
        P[rr][4] = __shfl_down(P[rr][0], 1);   // col 4x+4 from lane x+1

    // conv1 -> pool (raw max) -> leaky: own pool cols {2x,2x+1}, 5 pool rows
    float p1o[2][5][2];
    #pragma unroll
    for (int c = 0; c < 2; ++c) {
        const float wa = w1r[c * 4 + 0], wb = w1r[c * 4 + 1];
        const float wc = w1r[c * 4 + 2], wd = w1r[c * 4 + 3];
        const float bb = b1r[c];
        #pragma unroll
        for (int pr = 0; pr < 5; ++pr)
        #pragma unroll
        for (int pc = 0; pc < 2; ++pc) {
            float mx = -3.4e38f;
            #pragma unroll
            for (int s = 0; s < 2; ++s)
            #pragma unroll
            for (int tt = 0; tt < 2; ++tt) {
                const int u = 2 * pr + s, v = 2 * pc + tt;
                const float raw = fmaf(wa, P[u][v], fmaf(wb, P[u][v + 1],
                                  fmaf(wc, P[u + 1][v], fmaf(wd, P[u + 1][v + 1], bb))));
                mx = fmaxf(mx, raw);
            }
            p1o[c][pr][pc] = leaky(mx);
        }
    }

    // pool col 2x+2 from lane x+1
    float p1[2][5][3];
    #pragma unroll
    for (int c = 0; c < 2; ++c)
    #pragma unroll
    for (int pr = 0; pr < 5; ++pr) {
        p1[c][pr][0] = p1o[c][pr][0];
        p1[c][pr][1] = p1o[c][pr][1];
        p1[c][pr][2] = __shfl_down(p1o[c][pr][0], 1);
    }

    // conv2 -> pool (raw max) -> leaky -> store, for 2 output rows
    #pragma unroll
    for (int oy = 0; oy < 2; ++oy) {
        const int y = y0 + oy;
        if (y >= 59) break;              // wave-uniform
        if (x < 59) {
            float* xrow = xbuf + (size_t)(r * BS + b) * XPAD + (size_t)(t * 2) * 3481
                          + y * 59 + x;
            #pragma unroll
            for (int c2 = 0; c2 < 2; ++c2) {
                float mx = -3.4e38f;
                #pragma unroll
                for (int a2 = 0; a2 < 2; ++a2)
                #pragma unroll
                for (int b2i = 0; b2i < 2; ++b2i) {
                    float acc = b2r[c2];
                    #pragma unroll
                    for (int c1 = 0; c1 < 2; ++c1)
                    #pragma unroll
                    for (int du = 0; du < 2; ++du)
                    #pragma unroll
                    for (int dv = 0; dv < 2; ++dv)
                        acc += w2r[((c2 * 2 + c1) * 2 + du) * 2 + dv]
                             * p1[c1][2 * oy + a2 + du][b2i + dv];
                    mx = fmaxf(mx, acc);
                }
                xrow[(size_t)c2 * 3481] = leaky(mx);
            }
        }
    }
}

// ---------------------------------------------------------------------------
// fc1 split-K GEMM v3: M-tile 64 -> grid (111,4) = 444 blocks, 64KB LDS,
// 2 blocks/CU -> ALL blocks resident in one generation (no dispatch
// serialization); W traffic halves vs M32. Async global_load_lds staging,
// linear LDS dest + XOR-swizzled source + matching swizzled reads (rule #21).
// Per thread: 4m x 4n accumulator. Tail-chunk patch as in v2 (offset 7656).
// ---------------------------------------------------------------------------
__global__ __launch_bounds__(256) void gemm_fc1_kernel(
    const float* __restrict__ xbuf, const float* __restrict__ fc1w,
    float* __restrict__ psum)
{
    const int kc   = blockIdx.x;
    const int mt   = blockIdx.y;         // 0..3
    const int tid  = threadIdx.x;
    const int w    = tid >> 6;
    const int l    = tid & 63;
    const int kbase = kc * KC;
    const int row0  = mt * 64;

    __shared__ __align__(16) float Xs[64 * 128];   // (m,k4,e) at m*128+(k4^(m&31))*4+e
    __shared__ __align__(16) float Ws[64 * 128];   // (n,k4,e) at n*128+(k4^(n&31))*4+e

    // stage X: 32 x 1KB async instrs (wave w issues 8)
    const int ml  = l >> 5;
    const int k4s = l & 31;
    #pragma unroll
    for (int i = 0; i < 8; ++i) {
        const int s  = w * 8 + i;        // 0..31
        const int m  = s * 2 + ml;       // 0..63
        const int k4 = k4s ^ (m & 31);
        gload_lds16(xbuf + (size_t)(row0 + m) * XPAD + kbase + k4 * 4,
                    Xs + s * 256);
    }
    // stage W: 32 x 1KB async instrs (wave w issues 8)
    const float* gmax = fc1w + ((size_t)60 * XDIM - 4);  // last aligned f4 in-bounds
    #pragma unroll
    for (int i = 0; i < 8; ++i) {
        const int s  = w * 8 + i;
        const int n  = s * 2 + ml;
        const int k4 = k4s ^ (n & 31);
        const float* g = fc1w + (size_t)n * XDIM + kbase + k4 * 4;
        if (g > gmax) g = gmax;          // n>=60 rows + tail-chunk OOB: clamp
        gload_lds16(g, Ws + s * 256);
    }
    __syncthreads();   // drains vmcnt(0)

    if (kc == NKCH - 1) {
        // patch (n=59, k4=1): LDS float offset 59*128 + (1^27)*4 = 7656
        if (tid < 3) Ws[7656 + tid] = fc1w[(size_t)59 * XDIM + 14084 + tid];
        if (tid == 3) Ws[7659] = 0.f;    // k=14087 pairs with X pad zero anyway
        __syncthreads();
    }

    const int ty = tid >> 4, tx = tid & 15;
    const int m0 = ty * 4;
    const float4* X4 = reinterpret_cast<const float4*>(Xs);
    const float4* W4 = reinterpret_cast<const float4*>(Ws);

    float acc[4][4];
    #pragma unroll
    for (int i = 0; i < 4; ++i)
    #pragma unroll
    for (int j = 0; j < 4; ++j) acc[i][j] = 0.f;

    #pragma unroll 2
    for (int k4 = 0; k4 < 32; ++k4) {
        float4 xv[4];
        #pragma unroll
        for (int i = 0; i < 4; ++i)
            xv[i] = X4[(m0 + i) * 32 + (k4 ^ ((m0 + i) & 31))];
        #pragma unroll
        for (int j = 0; j < 4; ++j) {
            const int n = tx + 16 * j;
            const float4 wv4 = W4[n * 32 + (k4 ^ (n & 31))];
            #pragma unroll
            for (int i = 0; i < 4; ++i)
                acc[i][j] += xv[i].x * wv4.x + xv[i].y * wv4.y
                           + xv[i].z * wv4.z + xv[i].w * wv4.w;
        }
    }

    float* po = psum + ((size_t)kc * 256 + row0) * 64;
    #pragma unroll
    for (int i = 0; i < 4; ++i)
    #pragma unroll
    for (int j = 0; j < 4; ++j)
        po[(size_t)(m0 + i) * 64 + tx + 16 * j] = acc[i][j];
}

// ---------------------------------------------------------------------------
// Tail: reduce psum over chunks, bias+leaky, fc2, fc3, * nu, sum over r.
// Grid 128, 512 thr = (rh 2) x (kq 4) x (n 64). Deterministic.
// Cols 60..63 of psum hold garbage (clamped W rows) — masked here.
// ---------------------------------------------------------------------------
__global__ __launch_bounds__(512) void fc_tail_kernel(
    const float* __restrict__ psum,
    const float* __restrict__ fc1b,
    const float* __restrict__ fc2w, const float* __restrict__ fc2b,
    const float* __restrict__ fc3w, const float* __restrict__ fc3b,
    const float* __restrict__ nu, float* __restrict__ out)
{
    const int b = blockIdx.x;
    const int tid = threadIdx.x;
    const int n  = tid & 63;
    const int kq = (tid >> 6) & 3;
    const int rh = tid >> 8;

    __shared__ float red[2][4][64];
    __shared__ float y1s[2][64];
    __shared__ float y2s[2][30];

    const int row = rh * 128 + b;
    float s = 0.f;
    for (int kcc = kq; kcc < NKCH; kcc += 4)
        s += psum[((size_t)kcc * 256 + row) * 64 + n];
    red[rh][kq][n] = s;
    __syncthreads();

    if (kq == 0) {
        float tt = red[rh][0][n] + red[rh][1][n] + red[rh][2][n] + red[rh][3][n];
        y1s[rh][n] = (n < 60) ? leaky(tt + fc1b[n]) : 0.f;
    }
    __syncthreads();

    if (kq == 0 && n < 30) {
        float a2 = fc2b[n];
        const float* wr = fc2w + n * 60;
        #pragma unroll
        for (int k = 0; k < 60; ++k) a2 += wr[k] * y1s[rh][k];
        y2s[rh][n] = leaky(a2);
    }
    __syncthreads();

    if (tid == 0) {
        float acc_out = 0.f;
        #pragma unroll
        for (int r = 0; r < 2; ++r) {
            float a3 = fc3b[0];
            #pragma unroll
            for (int k = 0; k < 30; ++k) a3 += fc3w[k] * y2s[r][k];
            acc_out += a3 * nu[b * 2 + r];
        }
        out[b] = acc_out;
    }
}

extern "C" void kernel_launch(void* const* d_in, const int* in_sizes, int n_in,
                              void* d_out, int out_size, void* d_ws, size_t ws_size,
                              hipStream_t stream)
{
    const float* xyz   = (const float*)d_in[0];
    const float* cn    = (const float*)d_in[1];
    const float* edisp = (const float*)d_in[2];
    const float* ovlp  = (const float*)d_in[3];
    const float* h0    = (const float*)d_in[4];
    const float* egfn1 = (const float*)d_in[5];
    const float* nu    = (const float*)d_in[6];
    const float* We1   = (const float*)d_in[7];
    const float* be1   = (const float*)d_in[8];
    const float* We2   = (const float*)d_in[9];
    const float* be2   = (const float*)d_in[10];
    // d_in[11..15] = Wc1,bc1,Wc2,bc2,coors_scale: dead code (coors_out discarded)
    const float* Wn1   = (const float*)d_in[16];
    const float* bn1   = (const float*)d_in[17];
    const float* Wn2   = (const float*)d_in[18];
    const float* bn2   = (const float*)d_in[19];
    const float* c1w   = (const float*)d_in[20];
    const float* c1b   = (const float*)d_in[21];
    const float* c2w   = (const float*)d_in[22];
    const float* c2b   = (const float*)d_in[23];
    const float* fc1w  = (const float*)d_in[24];
    const float* fc1b  = (const float*)d_in[25];
    const float* fc2w  = (const float*)d_in[26];
    const float* fc2b  = (const float*)d_in[27];
    const float* fc3w  = (const float*)d_in[28];
    const float* fc3b  = (const float*)d_in[29];

    float* xbuf = (float*)d_ws;                           // 256 x 14208 f32 = 14.55 MB
    float* psum = (float*)((char*)d_ws + (size_t)256 * XPAD * 4);  // 111x256x64 f32 = 7.27 MB
    float* out  = (float*)d_out;

    hipLaunchKernelGGL(padzero_kernel, dim3(256), dim3(128), 0, stream, xbuf);
    hipLaunchKernelGGL(egnn_kernel, dim3(256), dim3(512), 0, stream,
                       xyz, cn, edisp, egfn1, We1, be1, We2, be2,
                       Wn1, bn1, Wn2, bn2, xbuf);
    hipLaunchKernelGGL(conv_kernel, dim3(512 * 8), dim3(256), 0, stream,
                       ovlp, h0, c1w, c1b, c2w, c2b, xbuf);
    hipLaunchKernelGGL(gemm_fc1_kernel, dim3(NKCH, 4), dim3(256), 0, stream,
                       xbuf, fc1w, psum);
    hipLaunchKernelGGL(fc_tail_kernel, dim3(128), dim3(512), 0, stream,
                       psum, fc1b, fc2w, fc2b, fc3w, fc3b, nu, out);
}